// Round 10
// baseline (197.089 us; speedup 1.0000x reference)
//
#include <hip/hip_runtime.h>
#include <hip/hip_cooperative_groups.h>

#define T_SEQ 2048
#define DHEAD 128
#define NBH 16
#define SCALE 0.08838834764831845f

namespace cg = cooperative_groups;

typedef unsigned short u16;
typedef unsigned int u32;
typedef u16 u16x4 __attribute__((ext_vector_type(4)));
typedef u16 u16x8 __attribute__((ext_vector_type(8)));
typedef u32 u32x2 __attribute__((ext_vector_type(2)));
typedef short s16x4 __attribute__((ext_vector_type(4)));
typedef __bf16 bf16x8 __attribute__((ext_vector_type(8)));
typedef float f32x4 __attribute__((ext_vector_type(4)));

__device__ __forceinline__ u16 f2bfu(float x) {
  union { float f; unsigned u; } c; c.f = x;
  unsigned u = c.u;
  u = u + 0x7FFFu + ((u >> 16) & 1u);   // RNE
  return (u16)(u >> 16);
}

__device__ __forceinline__ bf16x8 ldsFrag(const u16* p) {
  u16x8 t = *(const u16x8*)p;
  return __builtin_bit_cast(bf16x8, t);
}

__device__ __forceinline__ f32x4 mfma16x16x16bf16(s16x4 a, s16x4 b, f32x4 c) {
#if __has_builtin(__builtin_amdgcn_mfma_f32_16x16x16bf16_1k)
  return __builtin_amdgcn_mfma_f32_16x16x16bf16_1k(a, b, c, 0, 0, 0);
#else
  asm("v_mfma_f32_16x16x16_bf16 %0, %1, %2, %0" : "+v"(c) : "v"(a), "v"(b));
  return c;
#endif
}

// ---------------------------------------------------------------------------
// FUSED mLSTM: one cooperative kernel, 256 blocks x 1024 thr (1 block/CU).
//   Phase 0: every block scans its own bh's gates (16x redundant, in-LDS:
//            ash=a, fsh=fc, cend=tile-end cummax).  No gate workspace.
//   Phase 1 (FAST): block (bh,p) converts K-tiles 2p,2p+1 -> kbf (scaled
//            bf16) and V -> vtbf (transposed bf16, direct global).
//            ONE grid.sync() makes kbf/vtbf visible to all blocks.
//   Phase 2: R9 main loop (proven 54us): UNIFORM 33 windows (tile A=31-p
//            then tile B=p), wave = kg(4)x rq(4), reg-staged 2-slot
//            ping-pong, compile-time oa indices, gate scalars from LDS.
// Rationale: the main loop is at a structural ~54us plateau (R3/R4/R7/R9
// all null); the other ~90us of the 148us bench is 3 serial launches +
// gaps + small-kernel inefficiency -> fusion removes it.
// LDS: Kst 2x32KB @0; osh @65536 (33792); rsh @99328 (2KB);
//      ash @101376 (8KB); fsh @109568 (8KB); cend @117760 (128B).
// ---------------------------------------------------------------------------
template <bool FAST>
__global__ __launch_bounds__(1024, 4) void mlstm_fused_kernel(
    const float* __restrict__ qg, const float* __restrict__ kxg,
    const float* __restrict__ vg, const float* __restrict__ ig,
    const float* __restrict__ fg, u16* __restrict__ kbf,
    u16* __restrict__ vtbf, float* __restrict__ out)
{
  const int bx = (int)blockIdx.x;
  const int bh = bx & 15, p = bx >> 4;
  const int tid = (int)threadIdx.x;
  const int w = tid >> 6, lane = tid & 63;
  const int quad = lane >> 4, l16 = lane & 15;
  const int kg = w & 3, rq = w >> 2;

  const int qtA = 31 - p, qtB = p;
  const int nA = qtA + 1;                 // nA + (qtB+1) == 33 for all p

  __shared__ __align__(16) unsigned char SM[117888];
  u16* Kst = (u16*)SM;                    // slot s: K @ s*16384(u16), V @ +8192
  float* osh  = (float*)(SM + 65536);
  float* rsh  = (float*)(SM + 99328);
  float* ash  = (float*)(SM + 101376);
  float* fsh  = (float*)(SM + 109568);
  float* cend = (float*)(SM + 117760);

  const size_t hoff = (size_t)bh * T_SEQ * DHEAD;

  // ================= phase 0: gate scan for own bh (in-LDS) ================
  {
    float* wsum = rsh;                    // 16 f32
    float* wmax = rsh + 16;               // 16 f32
    const int gbase = bh * T_SEQ + tid * 2;

    const float x0 = fg[gbase], x1 = fg[gbase + 1];
    const float ls0 = fminf(x0, 0.f) - log1pf(expf(-fabsf(x0)));
    const float ls1 = fminf(x1, 0.f) - log1pf(expf(-fabsf(x1)));
    const float s = ls0 + ls1;

    float sc = s;
#pragma unroll
    for (int off = 1; off < 64; off <<= 1) {
      const float t = __shfl_up(sc, off, 64);
      if (lane >= off) sc += t;
    }
    if (lane == 63) wsum[w] = sc;
    __syncthreads();
    float wo = 0.f;
#pragma unroll
    for (int i = 0; i < 15; ++i) if (i < w) wo += wsum[i];
    const float excl = wo + (sc - s);
    const float fc0 = excl + ls0;
    const float fc1 = excl + ls0 + ls1;
    fsh[tid * 2] = fc0; fsh[tid * 2 + 1] = fc1;
    const float a0 = ig[gbase] - fc0;
    const float a1 = ig[gbase + 1] - fc1;
    ash[tid * 2] = a0; ash[tid * 2 + 1] = a1;

    const float m = fmaxf(a0, a1);
    float mc = m;
#pragma unroll
    for (int off = 1; off < 64; off <<= 1) {
      const float t = __shfl_up(mc, off, 64);
      if (lane >= off) mc = fmaxf(mc, t);
    }
    if (lane == 63) wmax[w] = mc;
    __syncthreads();
    float wmo = -INFINITY;
#pragma unroll
    for (int i = 0; i < 15; ++i) if (i < w) wmo = fmaxf(wmo, wmax[i]);
    const float prev = __shfl_up(mc, 1, 64);
    float exclm = (lane > 0) ? prev : -INFINITY;
    exclm = fmaxf(exclm, wmo);
    const float c1v = fmaxf(exclm, m);
    if ((tid & 31) == 31) cend[(tid * 2 + 1) >> 6] = c1v;  // rows 63 mod 64
    __syncthreads();
  }

  // ============== phase 1 (FAST): cvt own 2 key-tiles + grid sync ==========
  if (FAST) {
#pragma unroll
    for (int t = 0; t < 2; ++t) {
      const int kt = 2 * p + t;
      {  // K_hat = K * exp(a - c_end), 8 elems/thread
        const int r = tid >> 4, ci = (tid & 15) * 8;
        const int row = kt * 64 + r;
        const float sc = __expf(ash[row] - cend[kt]);
        const float* sp = kxg + hoff + (size_t)row * DHEAD + ci;
        const float4 x0 = *(const float4*)sp;
        const float4 x1 = *(const float4*)(sp + 4);
        u16x8 pk;
        pk[0] = f2bfu(x0.x * sc); pk[1] = f2bfu(x0.y * sc);
        pk[2] = f2bfu(x0.z * sc); pk[3] = f2bfu(x0.w * sc);
        pk[4] = f2bfu(x1.x * sc); pk[5] = f2bfu(x1.y * sc);
        pk[6] = f2bfu(x1.z * sc); pk[7] = f2bfu(x1.w * sc);
        *(u16x8*)(kbf + hoff + (size_t)row * DHEAD + ci) = pk;
      }
      {  // V -> Vt transposed bf16 (coalesced f32 reads, 16B/lane writes)
        const int n = tid & 127, kb = tid >> 7;
        const float* vp = vg + hoff + (size_t)(kt * 64 + kb * 8) * DHEAD + n;
        u16x8 pw;
#pragma unroll
        for (int r8 = 0; r8 < 8; ++r8) pw[r8] = f2bfu(vp[(size_t)r8 * DHEAD]);
        *(u16x8*)(vtbf + (size_t)bh * DHEAD * T_SEQ + (size_t)n * T_SEQ
                  + kt * 64 + kb * 8) = pw;
      }
    }
    cg::this_grid().sync();
  }

  // ===================== phase 2: main loop (R9, proven) ===================
  const float cglr = cend[lane & 31];     // tile-end cummax, lane-indexed

  // Q -> B-frags qf[kc]: B[k=quad*8+j][n=l16], row = qt*64 + rq*16 + l16
  bf16x8 qf[4];
  auto loadQ = [&](int lqt) {
    const float* qp = qg + hoff + (size_t)(lqt * 64 + rq * 16 + l16) * DHEAD + quad * 8;
#pragma unroll
    for (int kc = 0; kc < 4; ++kc) {
      const float4 x0 = *(const float4*)(qp + kc * 32);
      const float4 x1 = *(const float4*)(qp + kc * 32 + 4);
      u16x8 t;
      t[0] = f2bfu(x0.x); t[1] = f2bfu(x0.y); t[2] = f2bfu(x0.z); t[3] = f2bfu(x0.w);
      t[4] = f2bfu(x1.x); t[5] = f2bfu(x1.y); t[6] = f2bfu(x1.z); t[7] = f2bfu(x1.w);
      qf[kc] = __builtin_bit_cast(bf16x8, t);
    }
  };

  f32x4 oa[8];                           // O^T partial: 8 vd-tiles x 16 rows
  float rsacc;
  auto zeroAcc = [&]() {
#pragma unroll
    for (int mt = 0; mt < 8; ++mt) oa[mt] = (f32x4){0.f, 0.f, 0.f, 0.f};
    rsacc = 0.f;
  };
  zeroAcc();

  // ---- staging addresses (loop-invariant) ----
  const int skey = tid >> 4, sdb = (tid & 15) ^ (skey & 7);
  const u16* ksBase = kbf + hoff + (size_t)skey * DHEAD + sdb * 8;
  const int svn = tid >> 3, svk = (tid & 7) ^ (svn & 7);
  const u16* vsBase = vtbf + (size_t)bh * DHEAD * T_SEQ + (size_t)svn * T_SEQ + svk * 8;

  auto stp = [&](int s) { return s < nA ? s : s - nA; };

  // issue global->reg loads for seq s (FAST only; 16B/lane coalesced)
  auto ld = [&](int s, u16x8& kr, u16x8& vr) {
    if (FAST) {
      const int st = stp(s);
      kr = *(const u16x8*)(ksBase + (size_t)st * 64 * DHEAD);
      vr = *(const u16x8*)(vsBase + st * 64);
    }
  };
  // write seq s into slot base KbL (reg data for FAST; full convert for slow)
  auto wr = [&](int s, u16x8 kr, u16x8 vr, u16* KbL) {
    if (FAST) {
      *(u16x8*)(KbL + tid * 8) = kr;
      *(u16x8*)(KbL + 8192 + tid * 8) = vr;
    } else {
      const int st = stp(s);
      const float ct = cend[st];
      const float* kp = kxg + hoff + (size_t)(st * 64 + skey) * DHEAD + sdb * 8;
      const float* vp = vg + hoff + (size_t)(st * 64) * DHEAD;
      const float scv = __expf(ash[st * 64 + skey] - ct);
      const float4 x0 = *(const float4*)kp;
      const float4 x1 = *(const float4*)(kp + 4);
      u16x8 pk;
      pk[0] = f2bfu(x0.x * scv); pk[1] = f2bfu(x0.y * scv);
      pk[2] = f2bfu(x0.z * scv); pk[3] = f2bfu(x0.w * scv);
      pk[4] = f2bfu(x1.x * scv); pk[5] = f2bfu(x1.y * scv);
      pk[6] = f2bfu(x1.z * scv); pk[7] = f2bfu(x1.w * scv);
      *(u16x8*)(KbL + tid * 8) = pk;
      u16x8 pw;
#pragma unroll
      for (int rr = 0; rr < 8; ++rr)
        pw[rr] = f2bfu(vp[(size_t)(svk * 8 + rr) * DHEAD + svn]);
      *(u16x8*)(KbL + 8192 + tid * 8) = pw;
    }
  };

  const int keyA = kg * 16 + l16;         // A-frag key row (QK)
  const int ksw  = l16 & 7;
  // vd&7 == l16&7 for all mt -> V swizzle is mt-invariant:
  const int vbase = l16 * 64 + (((kg * 2 + (quad >> 1)) ^ (l16 & 7)) * 8) + (quad & 1) * 4;

  auto computeStage = [&](int cqt, int st, const u16* KbL, float ccmax) {
    const u16* VbL = KbL + 8192;

    // ---- S^T = K_hat Q^T ----
    f32x4 sa = (f32x4){0.f, 0.f, 0.f, 0.f};
#pragma unroll
    for (int kc = 0; kc < 4; ++kc) {
      const bf16x8 kf = ldsFrag(KbL + keyA * 128 + (((kc * 4 + quad) ^ ksw) * 8));
      sa = __builtin_amdgcn_mfma_f32_16x16x32_bf16(kf, qf[kc], sa, 0, 0, 0);
    }

    const float etile = SCALE * __expf(__shfl(cglr, st, 64) - ccmax);
    float x0 = sa[0] * etile, x1 = sa[1] * etile;
    float x2 = sa[2] * etile, x3 = sa[3] * etile;
    if (st == cqt) {
      const int qr = rq * 16 + l16, kb0 = kg * 16 + quad * 4;
      if (kb0 + 0 > qr) x0 = 0.f;
      if (kb0 + 1 > qr) x1 = 0.f;
      if (kb0 + 2 > qr) x2 = 0.f;
      if (kb0 + 3 > qr) x3 = 0.f;
    }
    rsacc += (x0 + x1) + (x2 + x3);
    u32 plo, phi;
    asm("v_cvt_pk_bf16_f32 %0, %1, %2" : "=v"(plo) : "v"(x0), "v"(x1));
    asm("v_cvt_pk_bf16_f32 %0, %1, %2" : "=v"(phi) : "v"(x2), "v"(x3));
    const s16x4 pfr = __builtin_bit_cast(s16x4, (u32x2){plo, phi});

    // ---- O^T += V^T P^T ----
#pragma unroll
    for (int mt = 0; mt < 8; ++mt) {
      const s16x4 va = *(const s16x4*)(VbL + vbase + mt * 1024);
      oa[mt] = mfma16x16x16bf16(va, pfr, oa[mt]);
    }
  };

  auto epilogue = [&](int eqt, float ecmax) {
    float x = rsacc;
    x += __shfl_xor(x, 16, 64);
    x += __shfl_xor(x, 32, 64);
    if (lane < 16) rsh[kg * 64 + rq * 16 + lane] = x;
    __syncthreads();
    float inv = 0.f;
    if (kg == 3) {
      const int row = rq * 16 + l16;
      const float tot = rsh[row] + rsh[64 + row] + rsh[128 + row] + rsh[192 + row];
      const float nf = __expf(-(ecmax + fsh[eqt * 64 + row]));
      inv = 1.f / fmaxf(fabsf(tot), nf);
    }
    for (int r = 0; r < 4; ++r) {
      if (kg == r) {
        const int row = rq * 16 + l16;
#pragma unroll
        for (int mt = 0; mt < 8; ++mt) {
          float* ap = osh + row * 132 + mt * 16 + quad * 4;
          f32x4 vv = oa[mt];
          if (r > 0) vv = vv + *(const f32x4*)ap;
          if (r == 3) vv = vv * inv;
          *(f32x4*)ap = vv;
        }
      }
      __syncthreads();
    }
    const int col = tid & 31, r0 = tid >> 5;
#pragma unroll
    for (int i = 0; i < 2; ++i) {
      const int row = r0 + 32 * i;
      const f32x4 vv = *(const f32x4*)(osh + row * 132 + col * 4);
      *(f32x4*)(out + hoff + (size_t)(eqt * 64 + row) * DHEAD + col * 4) = vv;
    }
    __syncthreads();
  };

  // -------- prologue --------
  int qt = qtA;
  float cmax = __shfl(cglr, qtA, 64);
  loadQ(qtA);
  u16x8 k0, v0, k1, v1;                   // parity-named staging buffers
  ld(0, k0, v0);
  wr(0, k0, v0, Kst);                     // slot 0
  ld(1, k1, v1);
  __syncthreads();

  auto maybeTransition = [&](int it) {
    if (it == nA - 1) {
      loadQ(qtB);                         // qf is 16 regs: safe co-live (R1)
      epilogue(qtA, cmax);
      zeroAcc();
      qt = qtB;
      cmax = __shfl(cglr, qtB, 64);
    }
  };

  // -------- 33 uniform windows, hand-unrolled x2 for parity-static regs ----
  for (int g = 0; g < 17; ++g) {
    {                                      // even window it = 2g, slot 0
      const int it = 2 * g;
      if (it < 32) wr(it + 1, k1, v1, Kst + 16384);   // slot 1
      if (it + 2 < 33) ld(it + 2, k0, v0);
      computeStage(qt, stp(it), Kst, cmax);
      __syncthreads();
      maybeTransition(it);
    }
    if (2 * g + 1 < 33) {                  // odd window it = 2g+1, slot 1
      const int it = 2 * g + 1;
      if (it < 32) wr(it + 1, k0, v0, Kst);           // slot 0
      if (it + 2 < 33) ld(it + 2, k1, v1);
      computeStage(qt, stp(it), Kst + 16384, cmax);
      __syncthreads();
      maybeTransition(it);
    }
  }
  epilogue(qtB, cmax);
}

// ---------------------------------------------------------------------------
extern "C" void kernel_launch(void* const* d_in, const int* in_sizes, int n_in,
                              void* d_out, int out_size, void* d_ws, size_t ws_size,
                              hipStream_t stream) {
  const float* q  = (const float*)d_in[0];
  const float* k  = (const float*)d_in[1];
  const float* v  = (const float*)d_in[2];
  const float* ig = (const float*)d_in[3];
  const float* fg = (const float*)d_in[4];

  const size_t kv_elems = (size_t)NBH * T_SEQ * DHEAD;
  const bool fast = ws_size >= 2 * kv_elems * sizeof(u16);

  u16* kbf  = (u16*)d_ws;
  u16* vtbf = kbf + kv_elems;
  float* outp = (float*)d_out;

  if (fast) {
    void* args[] = {(void*)&q, (void*)&k, (void*)&v, (void*)&ig, (void*)&fg,
                    (void*)&kbf, (void*)&vtbf, (void*)&outp};
    hipLaunchCooperativeKernel(
        reinterpret_cast<void*>(mlstm_fused_kernel<true>),
        dim3(256), dim3(1024), args, 0, stream);
  } else {
    mlstm_fused_kernel<false><<<dim3(256), dim3(1024), 0, stream>>>(
        q, k, v, ig, fg, kbf, vtbf, outp);
  }
}